// Round 2
// baseline (465.713 us; speedup 1.0000x reference)
//
#include <hip/hip_runtime.h>
#include <hip/hip_bf16.h>
#include <math.h>

// BS=1, L=2048, D=4096. r13 measured 503.2us (tiered, all-bf16 DMA staging).
// r14b: GEMM2 (S = Q*context^T, 4096x4096x2048 — the only full-fill 256-block
// shape) ported to the 256^2/BK=64 counted-vmcnt phase template:
//  - 2x double-buffered 128KiB LDS, 8 waves (2Mx4N), 16x16x32 bf16 MFMA
//  - T2: row-XOR bank swizzle (byte ^= (row&7)<<4), applied as pre-swizzled
//    GLOBAL source for global_load_lds + same XOR on ds_read (both-sides rule)
//  - T3/T4: 4 phases/K-tile, chunk issue order [A0,A2|B0,B1|B2,B3|A1,A3],
//    steady-state waits vmcnt(4) @p1-end, vmcnt(2) @p3-end — never 0 in loop
//  - T5: s_setprio(1) around each 16-MFMA cluster; raw s_barrier
//  - T1: XCD-aware bijective swizzle of the 16x16 grid
// r14b audit fix vs r14: DMA LDS dest is now WAVE-UNIFORM (lb + wid*512),
// matching the m104/m108 rule and the proven mfma_gemm pattern; r14 passed a
// lane-varying LDS pointer (worked only if scalarized via readfirstlane).

typedef __attribute__((ext_vector_type(8))) short short8;
typedef __attribute__((ext_vector_type(4))) float f32x4;

__device__ __forceinline__ unsigned short f2bf(float f) {
  unsigned u = __float_as_uint(f);
  return (unsigned short)((u + 0x7FFF + ((u >> 16) & 1)) >> 16);  // RNE
}

typedef const __attribute__((address_space(1))) unsigned int* gas_t;
typedef __attribute__((address_space(3))) unsigned int* las_t;
__device__ __forceinline__ void dma16(const unsigned short* g, unsigned short* l)
{
  __builtin_amdgcn_global_load_lds((gas_t)(const void*)g, (las_t)(void*)l,
                                   16, 0, 0);
}

// ---------------------------------------------------------------------------
// 256x256-tile, BK=64, counted-vmcnt 4-phase GEMM (C fp32 out).
// C[i][j] = sum_k A[i][k]*B[j][k], both bf16 k-major. Grid must be 256 blocks
// (M=N=4096). LDS 128KiB -> 1 block/CU -> exact machine fill.
// ---------------------------------------------------------------------------
__global__ __launch_bounds__(512, 2) void gemm256(
    const unsigned short* __restrict__ A, const unsigned short* __restrict__ B,
    float* __restrict__ C, int K, int lda, int ldb, int ldc)
{
  // [buf][0=A,1=B][256 rows][64 cols] bf16, row = 128B. Total 131072 B.
  __shared__ unsigned short sm[2][2][256 * 64];
  const int t = threadIdx.x;
  const int lane = t & 63;
  const int wid = t >> 6;
  const int wr = wid >> 2;          // 0..1  (M half)
  const int wc = wid & 3;           // 0..3  (N quarter)
  const int lr = lane & 15, lq = lane >> 4;

  // T1: XCD-aware swizzle; XCD x = wg&7 gets a compact 4x8 region of the
  // 16x16 grid (bijective; 256 % 8 == 0).
  int bx, by;
  {
    int wg = blockIdx.x;
    int x = wg & 7, s = wg >> 3;
    by = (x & 3) * 4 + (s >> 3);
    bx = (x >> 2) * 8 + (s & 7);
  }
  const int i0 = by * 256, j0 = bx * 256;

  // Staging geometry: chunk = 64 rows x 64 cols bf16 = 8KiB = 512 thr x 16B.
  // Linear LDS dest (gload_lds: wave-uniform base, HW adds lane*16B) +
  // pre-swizzled global source so physical LDS holds the XOR-swizzled layout.
  const int r_ = t >> 3;                       // row within chunk (0..63)
  const int ss_ = ((t & 7) ^ (r_ & 7)) * 8;    // swizzled source col (elems)

  // Issue one chunk's DMA. c: 0..3 = A rows c*64.., 4..7 = B rows (c-4)*64..
  auto issue = [&](int buf, int c, int k0) {
    const unsigned short* M;
    int ld, r0;
    if (c < 4) { M = A; ld = lda; r0 = i0 + (c & 3) * 64; }
    else       { M = B; ld = ldb; r0 = j0 + (c & 3) * 64; }
    unsigned short* lb = &sm[buf][c >> 2][(c & 3) * 4096];
    // dest: wave-uniform base (wave wid covers 16B-slots wid*64..wid*64+63)
    dma16(M + (size_t)(r0 + r_) * ld + k0 + ss_, lb + wid * 512);
  };

  // Swizzled fragment read: logical (row, khalf) -> 16B at XOR'd address.
  auto frag = [&](const unsigned short* mat, int row, int kh) -> short8 {
    int lb = row * 128 + kh * 64 + (lq << 4);
    int pb = lb ^ ((row & 7) << 4);
    return *(const short8*)((const char*)mat + pb);
  };

  f32x4 acc[8][4];
  #pragma unroll
  for (int a = 0; a < 8; a++)
    #pragma unroll
    for (int b = 0; b < 4; b++) acc[a][b] = (f32x4){0.f, 0.f, 0.f, 0.f};

  // Prologue: stage kt=0 into buf0 in steady-state order; leave A1,A3 in
  // flight (they are read only at phases 2-3, protected by W1).
  issue(0, 0, 0); issue(0, 2, 0);
  issue(0, 4, 0); issue(0, 5, 0);
  issue(0, 6, 0); issue(0, 7, 0);
  issue(0, 1, 0); issue(0, 3, 0);
  asm volatile("s_waitcnt vmcnt(2)" ::: "memory");
  __builtin_amdgcn_s_barrier();

  const int NT = K >> 6;
  for (int kt = 0; kt < NT; kt++) {
    const int cur = kt & 1;
    const unsigned short* As = sm[cur][0];
    const unsigned short* Bs = sm[cur][1];
    const int kn = (kt + 1) << 6;
    const bool st = (kt + 1 < NT);
    short8 bfr[4][2];

    #pragma unroll
    for (int p = 0; p < 4; p++) {
      // ---- ds reads for this phase (A rows p*32..p*32+31 of wave's half) --
      short8 a0k0 = frag(As, wr * 128 + (p * 2 + 0) * 16 + lr, 0);
      short8 a0k1 = frag(As, wr * 128 + (p * 2 + 0) * 16 + lr, 1);
      short8 a1k0 = frag(As, wr * 128 + (p * 2 + 1) * 16 + lr, 0);
      short8 a1k1 = frag(As, wr * 128 + (p * 2 + 1) * 16 + lr, 1);
      if (p == 0) {
        #pragma unroll
        for (int nf = 0; nf < 4; nf++) {
          bfr[nf][0] = frag(Bs, wc * 64 + nf * 16 + lr, 0);
          bfr[nf][1] = frag(Bs, wc * 64 + nf * 16 + lr, 1);
        }
      }
      // ---- issue next-tile DMA chunks (order: A0,A2 | B0,B1 | B2,B3 | A1,A3)
      if (st) {
        if (p == 0) { issue(cur ^ 1, 0, kn); issue(cur ^ 1, 2, kn); }
        if (p == 1) { issue(cur ^ 1, 4, kn); issue(cur ^ 1, 5, kn); }
        if (p == 2) { issue(cur ^ 1, 6, kn); issue(cur ^ 1, 7, kn); }
        if (p == 3) { issue(cur ^ 1, 1, kn); issue(cur ^ 1, 3, kn); }
      }
      asm volatile("" ::: "memory");
      __builtin_amdgcn_s_barrier();
      __builtin_amdgcn_s_setprio(1);
      #pragma unroll
      for (int nf = 0; nf < 4; nf++) {
        acc[p * 2 + 0][nf] = __builtin_amdgcn_mfma_f32_16x16x32_bf16(
            a0k0, bfr[nf][0], acc[p * 2 + 0][nf], 0, 0, 0);
        acc[p * 2 + 0][nf] = __builtin_amdgcn_mfma_f32_16x16x32_bf16(
            a0k1, bfr[nf][1], acc[p * 2 + 0][nf], 0, 0, 0);
        acc[p * 2 + 1][nf] = __builtin_amdgcn_mfma_f32_16x16x32_bf16(
            a1k0, bfr[nf][0], acc[p * 2 + 1][nf], 0, 0, 0);
        acc[p * 2 + 1][nf] = __builtin_amdgcn_mfma_f32_16x16x32_bf16(
            a1k1, bfr[nf][1], acc[p * 2 + 1][nf], 0, 0, 0);
      }
      __builtin_amdgcn_s_setprio(0);
      // W1: before phases 2-3 read A-odd chunks, their DMA (issued last
      // iteration's p3) must have landed in ALL threads: vmcnt then barrier.
      if (p == 1) {
        if (st) asm volatile("s_waitcnt vmcnt(4)" ::: "memory");
        else    asm volatile("s_waitcnt vmcnt(0)" ::: "memory");
      }
      // W2: before next iteration reads buf^1, chunks A0,A2,B0..B3 of kt+1
      // must have landed; A1,A3 stay in flight (6-deep).
      if (p == 3 && st) asm volatile("s_waitcnt vmcnt(2)" ::: "memory");
      asm volatile("" ::: "memory");
      __builtin_amdgcn_s_barrier();
    }
  }

  // C/D layout: col = lane&15, row = (lane>>4)*4 + reg.
  #pragma unroll
  for (int mf = 0; mf < 8; mf++)
    #pragma unroll
    for (int nf = 0; nf < 4; nf++)
      #pragma unroll
      for (int r = 0; r < 4; r++) {
        int row = i0 + wr * 128 + mf * 16 + lq * 4 + r;
        int col = j0 + wc * 64 + nf * 16 + lr;
        C[(size_t)row * ldc + col] = acc[mf][nf][r];
      }
}

// 128x128-tile bf16 MFMA GEMM: C[i][j] = sum_k A[i][k]*B[j][k], k-major both.
// A is always bf16 (DMA). BF32: 1 -> B fp32, VALU cvt staging; 0 -> bf16 DMA.
// CMODE: 0 -> C fp32; 1 -> C bf16; 2 -> colsum[j] += sum_i tanh(acc).
// LDS: no-pad [row][k] bf16, lane dest = vid*16B (contiguous; bank-floor).
template<int BF32, int CMODE>
__global__ __launch_bounds__(256) void mfma_gemm(
    const unsigned short* __restrict__ Abf, const void* __restrict__ Bv,
    void* __restrict__ Cv, float* __restrict__ colsum,
    int K, int lda, int ldb, int ldc)
{
  __shared__ unsigned short As[128 * 32];
  __shared__ unsigned short Bs[128 * 32];
  const int t = threadIdx.x;
  const int lane = t & 63, wid = t >> 6;
  const int wm = (wid >> 1) * 64, wn = (wid & 1) * 64;
  const int i0 = blockIdx.y * 128, j0 = blockIdx.x * 128;
  const int lr = lane & 15, lq = lane >> 4;

  f32x4 acc[4][4];
  #pragma unroll
  for (int a = 0; a < 4; a++)
    #pragma unroll
    for (int b = 0; b < 4; b++) acc[a][b] = (f32x4){0.f, 0.f, 0.f, 0.f};

  for (int k0 = 0; k0 < K; k0 += 32) {
    // ---- A staging: bf16 DMA (dest = wave base + lane*16) ----
    #pragma unroll
    for (int u = 0; u < 2; u++) {
      int vid = u * 256 + t;
      int row = vid >> 2, kq = (vid & 3) * 8;
      dma16(Abf + (size_t)(i0 + row) * lda + k0 + kq,
            &As[(u * 256 + wid * 64) * 8]);
    }
    // ---- B staging ----
    if (BF32 == 0) {
      #pragma unroll
      for (int u = 0; u < 2; u++) {
        int vid = u * 256 + t;
        int row = vid >> 2, kq = (vid & 3) * 8;
        dma16((const unsigned short*)Bv + (size_t)(j0 + row) * ldb + k0 + kq,
              &Bs[(u * 256 + wid * 64) * 8]);
      }
    } else {
      #pragma unroll
      for (int u = 0; u < 2; u++) {
        int vid = u * 256 + t;
        int row = vid >> 2, kq = (vid & 3) * 8;
        const float* s = (const float*)Bv + (size_t)(j0 + row) * ldb + k0 + kq;
        float4 f0 = *(const float4*)s;
        float4 f1 = *(const float4*)(s + 4);
        union { unsigned short h[8]; int4 v; } pk;
        pk.h[0] = f2bf(f0.x); pk.h[1] = f2bf(f0.y);
        pk.h[2] = f2bf(f0.z); pk.h[3] = f2bf(f0.w);
        pk.h[4] = f2bf(f1.x); pk.h[5] = f2bf(f1.y);
        pk.h[6] = f2bf(f1.z); pk.h[7] = f2bf(f1.w);
        *(int4*)&Bs[(size_t)vid * 8] = pk.v;   // vid*8 shorts == row*32+kq
      }
    }
    __syncthreads();   // drains vmcnt (DMA) + lgkmcnt before LDS reads

    short8 af[4], bfr[4];
    #pragma unroll
    for (int tm = 0; tm < 4; tm++)
      af[tm] = *(const short8*)&As[(wm + tm * 16 + lr) * 32 + lq * 8];
    #pragma unroll
    for (int tn = 0; tn < 4; tn++)
      bfr[tn] = *(const short8*)&Bs[(wn + tn * 16 + lr) * 32 + lq * 8];

    #pragma unroll
    for (int tm = 0; tm < 4; tm++)
      #pragma unroll
      for (int tn = 0; tn < 4; tn++)
        acc[tm][tn] = __builtin_amdgcn_mfma_f32_16x16x32_bf16(
            af[tm], bfr[tn], acc[tm][tn], 0, 0, 0);
    __syncthreads();
  }

  if (CMODE == 2) {
    // C/D layout: col=lane&15, row=lq*4+reg.
    #pragma unroll
    for (int tn = 0; tn < 4; tn++) {
      float s = 0.f;
      #pragma unroll
      for (int tm = 0; tm < 4; tm++)
        #pragma unroll
        for (int r = 0; r < 4; r++) s += tanhf(acc[tm][tn][r]);
      s += __shfl_xor(s, 16);
      s += __shfl_xor(s, 32);
      if (lq == 0) atomicAdd(&colsum[j0 + wn + tn * 16 + lr], s);
    }
  } else {
    #pragma unroll
    for (int tm = 0; tm < 4; tm++)
      #pragma unroll
      for (int tn = 0; tn < 4; tn++)
        #pragma unroll
        for (int r = 0; r < 4; r++) {
          int row = i0 + wm + tm * 16 + lq * 4 + r;
          int col = j0 + wn + tn * 16 + lr;
          if (CMODE == 0)
            ((float*)Cv)[(size_t)row * ldc + col] = acc[tm][tn][r];
          else
            ((unsigned short*)Cv)[(size_t)row * ldc + col] = f2bf(acc[tm][tn][r]);
        }
  }
}

// Tt_bf[key][l] = bf16(T[l][key]); T [2048][4096] fp32.
__global__ __launch_bounds__(256) void transpose_bf16(
    const float* __restrict__ T, unsigned short* __restrict__ Tt)
{
  __shared__ float tile[64][65];
  const int tx = threadIdx.x & 63;
  const int ty = threadIdx.x >> 6;
  const int k0 = blockIdx.x * 64;
  const int l0 = blockIdx.y * 64;
  #pragma unroll
  for (int u = 0; u < 16; u++) {
    int row = ty * 16 + u;
    tile[row][tx] = T[(size_t)(l0 + row) * 4096 + k0 + tx];
  }
  __syncthreads();
  #pragma unroll
  for (int u = 0; u < 16; u++) {
    int row = ty * 16 + u;
    Tt[(size_t)(k0 + row) * 2048 + l0 + tx] = f2bf(tile[tx][row]);
  }
}

// out[i] = bf16(in[i]), 8 elements/thread, packed 16B stores.
__global__ __launch_bounds__(256) void cvt_bf16(
    const float* __restrict__ in, unsigned short* __restrict__ out, int n8)
{
  int i = blockIdx.x * 256 + threadIdx.x;
  if (i >= n8) return;
  float4 f0 = ((const float4*)in)[(size_t)i * 2];
  float4 f1 = ((const float4*)in)[(size_t)i * 2 + 1];
  union { unsigned short h[8]; int4 v; } pk;
  pk.h[0] = f2bf(f0.x); pk.h[1] = f2bf(f0.y);
  pk.h[2] = f2bf(f0.z); pk.h[3] = f2bf(f0.w);
  pk.h[4] = f2bf(f1.x); pk.h[5] = f2bf(f1.y);
  pk.h[6] = f2bf(f1.z); pk.h[7] = f2bf(f1.w);
  ((int4*)out)[i] = pk.v;
}

// Row softmax over 4096 fp32, writes bf16 IN PLACE at row start.
__global__ __launch_bounds__(256) void softmax_bf16(float* __restrict__ S)
{
  float* p = S + (size_t)blockIdx.x * 4096;
  const int tid = threadIdx.x;
  float4 v[4];
  #pragma unroll
  for (int u = 0; u < 4; u++) v[u] = ((const float4*)p)[tid * 4 + u];

  float m = -3.4e38f;
  #pragma unroll
  for (int u = 0; u < 4; u++)
    m = fmaxf(m, fmaxf(fmaxf(v[u].x, v[u].y), fmaxf(v[u].z, v[u].w)));
  #pragma unroll
  for (int off = 32; off > 0; off >>= 1) m = fmaxf(m, __shfl_down(m, off, 64));
  __shared__ float redm[4];
  if ((tid & 63) == 0) redm[tid >> 6] = m;
  __syncthreads();
  m = fmaxf(fmaxf(redm[0], redm[1]), fmaxf(redm[2], redm[3]));

  float s = 0.f;
  #pragma unroll
  for (int u = 0; u < 4; u++) {
    v[u].x = __expf(v[u].x - m); v[u].y = __expf(v[u].y - m);
    v[u].z = __expf(v[u].z - m); v[u].w = __expf(v[u].w - m);
    s += v[u].x + v[u].y + v[u].z + v[u].w;
  }
  #pragma unroll
  for (int off = 32; off > 0; off >>= 1) s += __shfl_down(s, off, 64);
  __shared__ float reds[4];
  if ((tid & 63) == 0) reds[tid >> 6] = s;
  __syncthreads();
  s = reds[0] + reds[1] + reds[2] + reds[3];
  const float inv = 1.f / s;

  unsigned short* a = (unsigned short*)p;
  #pragma unroll
  for (int h = 0; h < 2; h++) {
    union { unsigned short u[8]; int4 q; } pk;
    #pragma unroll
    for (int j = 0; j < 2; j++) {
      float4 w = v[h * 2 + j];
      pk.u[j * 4 + 0] = f2bf(w.x * inv); pk.u[j * 4 + 1] = f2bf(w.y * inv);
      pk.u[j * 4 + 2] = f2bf(w.z * inv); pk.u[j * 4 + 3] = f2bf(w.w * inv);
    }
    ((int4*)a)[tid * 2 + h] = pk.q;
  }
}

__global__ void zero_k(float* p, int n)
{
  int i = blockIdx.x * 256 + threadIdx.x;
  if (i < n) p[i] = 0.f;
}

// scores /= max; softmax; -> FP32 out (2048).
__global__ __launch_bounds__(256) void finalize_k(const float* __restrict__ scores,
                                                  float* __restrict__ out)
{
  const int tid = threadIdx.x;
  float s[8];
  #pragma unroll
  for (int u = 0; u < 8; u++) s[u] = scores[tid + u * 256];

  __shared__ float red[4];

  float m = -3.4e38f;
  #pragma unroll
  for (int u = 0; u < 8; u++) m = fmaxf(m, s[u]);
  #pragma unroll
  for (int off = 32; off > 0; off >>= 1) m = fmaxf(m, __shfl_down(m, off, 64));
  if ((tid & 63) == 0) red[tid >> 6] = m;
  __syncthreads();
  m = fmaxf(fmaxf(red[0], red[1]), fmaxf(red[2], red[3]));
  __syncthreads();

  const float inv1 = 1.f / m;
  #pragma unroll
  for (int u = 0; u < 8; u++) s[u] *= inv1;

  float m2 = -3.4e38f;
  #pragma unroll
  for (int u = 0; u < 8; u++) m2 = fmaxf(m2, s[u]);
  #pragma unroll
  for (int off = 32; off > 0; off >>= 1) m2 = fmaxf(m2, __shfl_down(m2, off, 64));
  if ((tid & 63) == 0) red[tid >> 6] = m2;
  __syncthreads();
  m2 = fmaxf(fmaxf(red[0], red[1]), fmaxf(red[2], red[3]));
  __syncthreads();

  float sum = 0.f;
  #pragma unroll
  for (int u = 0; u < 8; u++) { s[u] = expf(s[u] - m2); sum += s[u]; }
  #pragma unroll
  for (int off = 32; off > 0; off >>= 1) sum += __shfl_down(sum, off, 64);
  if ((tid & 63) == 0) red[tid >> 6] = sum;
  __syncthreads();
  sum = red[0] + red[1] + red[2] + red[3];

  const float invs = 1.f / sum;
  #pragma unroll
  for (int u = 0; u < 8; u++)
    out[tid + u * 256] = s[u] * invs;
}

extern "C" void kernel_launch(void* const* d_in, const int* in_sizes, int n_in,
                              void* d_out, int out_size, void* d_ws, size_t ws_size,
                              hipStream_t stream)
{
  const float* T    = (const float*)d_in[0];   // [2048][4096]
  const float* Win  = (const float*)d_in[1];   // [2048][2048] 'ml'
  const float* Wout = (const float*)d_in[2];   // [2048][4096] 'lc'
  float* out = (float*)d_out;

  // tier1 fixed: Tt(16.78M) Tb(16.78M) Winb(8.39M) Woutb(16.78M) comb(33.55M)
  const size_t FIX1 = 92274688ull + 16384;
  int R = 1024; bool pre = false;
  if      (ws_size >= FIX1 + (size_t)4096 * 16384) { pre = true; R = 4096; }
  else if (ws_size >= FIX1 + (size_t)2048 * 16384) { pre = true; R = 2048; }
  else if (ws_size >= FIX1 + (size_t)1024 * 16384) { pre = true; R = 1024; }

  unsigned short* Tt = (unsigned short*)d_ws;

  if (pre) {
    unsigned short* Tb    = Tt + (size_t)4096 * 2048;
    unsigned short* Winb  = Tb + (size_t)2048 * 4096;
    unsigned short* Woutb = Winb + (size_t)2048 * 2048;
    unsigned short* comb  = Woutb + (size_t)2048 * 4096;
    float* S      = (float*)(comb + (size_t)4096 * 4096);
    float* scores = S + (size_t)R * 4096;

    zero_k<<<8, 256, 0, stream>>>(scores, 2048);
    transpose_bf16<<<dim3(64, 32), 256, 0, stream>>>(T, Tt);
    cvt_bf16<<<4096, 256, 0, stream>>>(T, Tb, 1048576);
    cvt_bf16<<<2048, 256, 0, stream>>>(Win, Winb, 524288);
    cvt_bf16<<<4096, 256, 0, stream>>>(Wout, Woutb, 1048576);

    // GEMM1: Q -> comb[:,2048:]
    mfma_gemm<0, 1><<<dim3(16, 32), 256, 0, stream>>>(
        Tt, Winb, comb + 2048, nullptr, 2048, 2048, 2048, 4096);
    for (int c = 0; c < 4096 / R; c++) {
      const size_t d0 = (size_t)c * R;
      if (R == 4096) {
        // full-fill 256-block shape -> counted-vmcnt 256^2 template
        gemm256<<<256, 512, 0, stream>>>(
            comb + 2048, Tt, S, 2048, 4096, 2048, 4096);
      } else {
        mfma_gemm<0, 0><<<dim3(32, R / 128), 256, 0, stream>>>(
            comb + d0 * 4096 + 2048, Tt, S, nullptr, 2048, 4096, 2048, 4096);
      }
      softmax_bf16<<<R, 256, 0, stream>>>(S);
      mfma_gemm<0, 1><<<dim3(16, R / 128), 256, 0, stream>>>(
          (unsigned short*)S, Tb, comb + d0 * 4096, nullptr, 4096, 8192, 4096, 4096);
    }
    mfma_gemm<0, 2><<<dim3(16, 32), 256, 0, stream>>>(
        comb, Woutb, nullptr, scores, 4096, 4096, 4096, 4096);
    finalize_k<<<1, 256, 0, stream>>>(scores, out);
  } else {
    // tier0: r12 layout (67,117,056 B proven to fit), inline cvt for fp32 B.
    unsigned short* comb = Tt + (size_t)4096 * 2048;
    float* S      = (float*)(comb + (size_t)4096 * 4096);
    float* scores = S + (size_t)1024 * 4096;

    zero_k<<<8, 256, 0, stream>>>(scores, 2048);
    transpose_bf16<<<dim3(64, 32), 256, 0, stream>>>(T, Tt);

    mfma_gemm<1, 1><<<dim3(16, 32), 256, 0, stream>>>(
        Tt, Win, comb + 2048, nullptr, 2048, 2048, 2048, 4096);
    for (int c = 0; c < 4; c++) {
      const size_t d0 = (size_t)c * 1024;
      mfma_gemm<0, 0><<<dim3(32, 8), 256, 0, stream>>>(
          comb + d0 * 4096 + 2048, Tt, S, nullptr, 2048, 4096, 2048, 4096);
      softmax_bf16<<<1024, 256, 0, stream>>>(S);
      mfma_gemm<1, 1><<<dim3(16, 8), 256, 0, stream>>>(
          (unsigned short*)S, T, comb + d0 * 4096, nullptr, 4096, 8192, 4096, 4096);
    }
    mfma_gemm<1, 2><<<dim3(16, 32), 256, 0, stream>>>(
        comb, Wout, nullptr, scores, 4096, 4096, 4096, 4096);
    finalize_k<<<1, 256, 0, stream>>>(scores, out);
  }
}

// Round 3
// 405.265 us; speedup vs baseline: 1.1492x; 1.1492x over previous
//
#include <hip/hip_runtime.h>
#include <hip/hip_bf16.h>
#include <math.h>

// BS=1, L=2048, D=4096. r14b measured 465.7us (gemm256 for GEMM2 verified).
// r15: port GEMM1/GEMM3/GEMM4 (all N=2048) to a BM=256xBN=128 variant of the
// verified counted-vmcnt template (gemm_n128): grid 16x16=256 blocks = exact
// machine fill, 96KiB dbuf LDS, 8 waves 2Mx4N (per-wave 128x32), 2 phases per
// K-tile x 16 MFMA, waits vmcnt(4)@q0 / vmcnt(2)@q1 (never 0 in loop), same
// XOR bank swizzle + wave-uniform DMA dest + XCD grid swizzle as gemm256.
// CMODE=1 -> bf16 C (GEMM1, GEMM3); CMODE=2 -> colsum += tanh (GEMM4).
// r14b counters: mfma_gemm 119us/dispatch, MfmaUtil 23%, 8.39M bank conflicts
// -> these three dispatches were ~300us of the 465.

typedef __attribute__((ext_vector_type(8))) short short8;
typedef __attribute__((ext_vector_type(4))) float f32x4;

__device__ __forceinline__ unsigned short f2bf(float f) {
  unsigned u = __float_as_uint(f);
  return (unsigned short)((u + 0x7FFF + ((u >> 16) & 1)) >> 16);  // RNE
}

typedef const __attribute__((address_space(1))) unsigned int* gas_t;
typedef __attribute__((address_space(3))) unsigned int* las_t;
__device__ __forceinline__ void dma16(const unsigned short* g, unsigned short* l)
{
  __builtin_amdgcn_global_load_lds((gas_t)(const void*)g, (las_t)(void*)l,
                                   16, 0, 0);
}

// ---------------------------------------------------------------------------
// 256x256-tile, BK=64, counted-vmcnt 4-phase GEMM (C fp32 out). GEMM2 only.
// ---------------------------------------------------------------------------
__global__ __launch_bounds__(512, 2) void gemm256(
    const unsigned short* __restrict__ A, const unsigned short* __restrict__ B,
    float* __restrict__ C, int K, int lda, int ldb, int ldc)
{
  __shared__ unsigned short sm[2][2][256 * 64];
  const int t = threadIdx.x;
  const int lane = t & 63;
  const int wid = t >> 6;
  const int wr = wid >> 2;
  const int wc = wid & 3;
  const int lr = lane & 15, lq = lane >> 4;

  int bx, by;
  {
    int wg = blockIdx.x;
    int x = wg & 7, s = wg >> 3;
    by = (x & 3) * 4 + (s >> 3);
    bx = (x >> 2) * 8 + (s & 7);
  }
  const int i0 = by * 256, j0 = bx * 256;

  const int r_ = t >> 3;
  const int ss_ = ((t & 7) ^ (r_ & 7)) * 8;

  auto issue = [&](int buf, int c, int k0) {
    const unsigned short* M;
    int ld, r0;
    if (c < 4) { M = A; ld = lda; r0 = i0 + (c & 3) * 64; }
    else       { M = B; ld = ldb; r0 = j0 + (c & 3) * 64; }
    unsigned short* lb = &sm[buf][c >> 2][(c & 3) * 4096];
    dma16(M + (size_t)(r0 + r_) * ld + k0 + ss_, lb + wid * 512);
  };

  auto frag = [&](const unsigned short* mat, int row, int kh) -> short8 {
    int lb = row * 128 + kh * 64 + (lq << 4);
    int pb = lb ^ ((row & 7) << 4);
    return *(const short8*)((const char*)mat + pb);
  };

  f32x4 acc[8][4];
  #pragma unroll
  for (int a = 0; a < 8; a++)
    #pragma unroll
    for (int b = 0; b < 4; b++) acc[a][b] = (f32x4){0.f, 0.f, 0.f, 0.f};

  issue(0, 0, 0); issue(0, 2, 0);
  issue(0, 4, 0); issue(0, 5, 0);
  issue(0, 6, 0); issue(0, 7, 0);
  issue(0, 1, 0); issue(0, 3, 0);
  asm volatile("s_waitcnt vmcnt(2)" ::: "memory");
  __builtin_amdgcn_s_barrier();

  const int NT = K >> 6;
  for (int kt = 0; kt < NT; kt++) {
    const int cur = kt & 1;
    const unsigned short* As = sm[cur][0];
    const unsigned short* Bs = sm[cur][1];
    const int kn = (kt + 1) << 6;
    const bool st = (kt + 1 < NT);
    short8 bfr[4][2];

    #pragma unroll
    for (int p = 0; p < 4; p++) {
      short8 a0k0 = frag(As, wr * 128 + (p * 2 + 0) * 16 + lr, 0);
      short8 a0k1 = frag(As, wr * 128 + (p * 2 + 0) * 16 + lr, 1);
      short8 a1k0 = frag(As, wr * 128 + (p * 2 + 1) * 16 + lr, 0);
      short8 a1k1 = frag(As, wr * 128 + (p * 2 + 1) * 16 + lr, 1);
      if (p == 0) {
        #pragma unroll
        for (int nf = 0; nf < 4; nf++) {
          bfr[nf][0] = frag(Bs, wc * 64 + nf * 16 + lr, 0);
          bfr[nf][1] = frag(Bs, wc * 64 + nf * 16 + lr, 1);
        }
      }
      if (st) {
        if (p == 0) { issue(cur ^ 1, 0, kn); issue(cur ^ 1, 2, kn); }
        if (p == 1) { issue(cur ^ 1, 4, kn); issue(cur ^ 1, 5, kn); }
        if (p == 2) { issue(cur ^ 1, 6, kn); issue(cur ^ 1, 7, kn); }
        if (p == 3) { issue(cur ^ 1, 1, kn); issue(cur ^ 1, 3, kn); }
      }
      asm volatile("" ::: "memory");
      __builtin_amdgcn_s_barrier();
      __builtin_amdgcn_s_setprio(1);
      #pragma unroll
      for (int nf = 0; nf < 4; nf++) {
        acc[p * 2 + 0][nf] = __builtin_amdgcn_mfma_f32_16x16x32_bf16(
            a0k0, bfr[nf][0], acc[p * 2 + 0][nf], 0, 0, 0);
        acc[p * 2 + 0][nf] = __builtin_amdgcn_mfma_f32_16x16x32_bf16(
            a0k1, bfr[nf][1], acc[p * 2 + 0][nf], 0, 0, 0);
        acc[p * 2 + 1][nf] = __builtin_amdgcn_mfma_f32_16x16x32_bf16(
            a1k0, bfr[nf][0], acc[p * 2 + 1][nf], 0, 0, 0);
        acc[p * 2 + 1][nf] = __builtin_amdgcn_mfma_f32_16x16x32_bf16(
            a1k1, bfr[nf][1], acc[p * 2 + 1][nf], 0, 0, 0);
      }
      __builtin_amdgcn_s_setprio(0);
      if (p == 1) {
        if (st) asm volatile("s_waitcnt vmcnt(4)" ::: "memory");
        else    asm volatile("s_waitcnt vmcnt(0)" ::: "memory");
      }
      if (p == 3 && st) asm volatile("s_waitcnt vmcnt(2)" ::: "memory");
      asm volatile("" ::: "memory");
      __builtin_amdgcn_s_barrier();
    }
  }

  #pragma unroll
  for (int mf = 0; mf < 8; mf++)
    #pragma unroll
    for (int nf = 0; nf < 4; nf++)
      #pragma unroll
      for (int r = 0; r < 4; r++) {
        int row = i0 + wr * 128 + mf * 16 + lq * 4 + r;
        int col = j0 + wc * 64 + nf * 16 + lr;
        C[(size_t)row * ldc + col] = acc[mf][nf][r];
      }
}

// ---------------------------------------------------------------------------
// r15: BM=256 x BN=128, BK=64, counted-vmcnt 2-phase GEMM. Grid must be
// (M/256)*(N/128) = 16*16 = 256 blocks. LDS 96KiB dbuf -> 1 block/CU.
// C[i][j] = sum_k A[i][k]*B[j][k], both bf16 k-major.
// CMODE 1: C bf16 out. CMODE 2: colsum[j] += sum_i tanh(acc).
// Wait ledger (verified): entry invariant = 2 in-flight (cur A1,A3).
//   q0: read A-even+B, issue next A0,A2,B0,B1 (6 out), MFMA mf0-3,
//       wait vmcnt(4) -> drains cur A1,A3; barrier.
//   q1: read A-odd, issue next A1,A3 (6 out), MFMA mf4-7,
//       wait vmcnt(2) -> drains next A0,A2,B0,B1; barrier.
// ---------------------------------------------------------------------------
template<int CMODE>
__global__ __launch_bounds__(512, 2) void gemm_n128(
    const unsigned short* __restrict__ A, const unsigned short* __restrict__ B,
    void* __restrict__ Cv, float* __restrict__ colsum,
    int K, int lda, int ldb, int ldc)
{
  // chunks: c0..c3 = A rows c*64 (32KiB); c4,c5 = B rows (c-4)*64 (16KiB)
  __shared__ unsigned short sm[2][384 * 64];
  const int t = threadIdx.x;
  const int lane = t & 63, wid = t >> 6;
  const int wr = wid >> 2;          // 0..1 (M half: 128 rows)
  const int wc = wid & 3;           // 0..3 (N quarter: 32 cols)
  const int lr = lane & 15, lq = lane >> 4;

  int bx, by;
  {
    int wg = blockIdx.x;
    int x = wg & 7, s = wg >> 3;
    by = (x & 3) * 4 + (s >> 3);
    bx = (x >> 2) * 8 + (s & 7);
  }
  const int i0 = by * 256, j0 = bx * 128;

  const int r_ = t >> 3;                       // row within chunk (0..63)
  const int ss_ = ((t & 7) ^ (r_ & 7)) * 8;    // swizzled source col (elems)

  auto issue = [&](int buf, int c, int k0) {
    const unsigned short* M;
    int ld, r0;
    if (c < 4) { M = A; ld = lda; r0 = i0 + c * 64; }
    else       { M = B; ld = ldb; r0 = j0 + (c - 4) * 64; }
    unsigned short* lb = &sm[buf][c * 4096];
    dma16(M + (size_t)(r0 + r_) * ld + k0 + ss_, lb + wid * 512);
  };

  auto frag = [&](const unsigned short* mat, int row, int kh) -> short8 {
    int lb = row * 128 + kh * 64 + (lq << 4);
    int pb = lb ^ ((row & 7) << 4);
    return *(const short8*)((const char*)mat + pb);
  };

  f32x4 acc[8][2];
  #pragma unroll
  for (int a = 0; a < 8; a++)
    #pragma unroll
    for (int b = 0; b < 2; b++) acc[a][b] = (f32x4){0.f, 0.f, 0.f, 0.f};

  // Prologue: q0-needs first, A-odd last; leave A1,A3 in flight.
  issue(0, 0, 0); issue(0, 2, 0);
  issue(0, 4, 0); issue(0, 5, 0);
  issue(0, 1, 0); issue(0, 3, 0);
  asm volatile("s_waitcnt vmcnt(2)" ::: "memory");
  __builtin_amdgcn_s_barrier();

  const int NT = K >> 6;
  for (int kt = 0; kt < NT; kt++) {
    const int cur = kt & 1;
    const unsigned short* As = sm[cur];
    const unsigned short* Bs = sm[cur] + 256 * 64;   // B rows 0..127
    const int kn = (kt + 1) << 6;
    const bool st = (kt + 1 < NT);

    short8 af[4][2], bfr[2][2];
    // ---- q0: A rows wr*128 + (0..3)*16, all B ----
    #pragma unroll
    for (int m = 0; m < 4; m++) {
      af[m][0] = frag(As, wr * 128 + m * 16 + lr, 0);
      af[m][1] = frag(As, wr * 128 + m * 16 + lr, 1);
    }
    #pragma unroll
    for (int n = 0; n < 2; n++) {
      bfr[n][0] = frag(Bs, wc * 32 + n * 16 + lr, 0);
      bfr[n][1] = frag(Bs, wc * 32 + n * 16 + lr, 1);
    }
    if (st) {
      issue(cur ^ 1, 0, kn); issue(cur ^ 1, 2, kn);
      issue(cur ^ 1, 4, kn); issue(cur ^ 1, 5, kn);
    }
    asm volatile("" ::: "memory");
    __builtin_amdgcn_s_barrier();
    __builtin_amdgcn_s_setprio(1);
    #pragma unroll
    for (int m = 0; m < 4; m++)
      #pragma unroll
      for (int n = 0; n < 2; n++) {
        acc[m][n] = __builtin_amdgcn_mfma_f32_16x16x32_bf16(
            af[m][0], bfr[n][0], acc[m][n], 0, 0, 0);
        acc[m][n] = __builtin_amdgcn_mfma_f32_16x16x32_bf16(
            af[m][1], bfr[n][1], acc[m][n], 0, 0, 0);
      }
    __builtin_amdgcn_s_setprio(0);
    if (st) asm volatile("s_waitcnt vmcnt(4)" ::: "memory");
    else    asm volatile("s_waitcnt vmcnt(0)" ::: "memory");
    asm volatile("" ::: "memory");
    __builtin_amdgcn_s_barrier();

    // ---- q1: A rows wr*128 + (4..7)*16 ----
    #pragma unroll
    for (int m = 0; m < 4; m++) {
      af[m][0] = frag(As, wr * 128 + (4 + m) * 16 + lr, 0);
      af[m][1] = frag(As, wr * 128 + (4 + m) * 16 + lr, 1);
    }
    if (st) { issue(cur ^ 1, 1, kn); issue(cur ^ 1, 3, kn); }
    asm volatile("" ::: "memory");
    __builtin_amdgcn_s_barrier();
    __builtin_amdgcn_s_setprio(1);
    #pragma unroll
    for (int m = 0; m < 4; m++)
      #pragma unroll
      for (int n = 0; n < 2; n++) {
        acc[4 + m][n] = __builtin_amdgcn_mfma_f32_16x16x32_bf16(
            af[m][0], bfr[n][0], acc[4 + m][n], 0, 0, 0);
        acc[4 + m][n] = __builtin_amdgcn_mfma_f32_16x16x32_bf16(
            af[m][1], bfr[n][1], acc[4 + m][n], 0, 0, 0);
      }
    __builtin_amdgcn_s_setprio(0);
    if (st) asm volatile("s_waitcnt vmcnt(2)" ::: "memory");
    asm volatile("" ::: "memory");
    __builtin_amdgcn_s_barrier();
  }

  if (CMODE == 2) {
    // C/D layout: col=lane&15, row=lq*4+reg.
    #pragma unroll
    for (int n = 0; n < 2; n++) {
      float s = 0.f;
      #pragma unroll
      for (int m = 0; m < 8; m++)
        #pragma unroll
        for (int r = 0; r < 4; r++) s += tanhf(acc[m][n][r]);
      s += __shfl_xor(s, 16);
      s += __shfl_xor(s, 32);
      if (lq == 0) atomicAdd(&colsum[j0 + wc * 32 + n * 16 + lr], s);
    }
  } else {
    #pragma unroll
    for (int m = 0; m < 8; m++)
      #pragma unroll
      for (int n = 0; n < 2; n++)
        #pragma unroll
        for (int r = 0; r < 4; r++) {
          int row = i0 + wr * 128 + m * 16 + lq * 4 + r;
          int col = j0 + wc * 32 + n * 16 + lr;
          ((unsigned short*)Cv)[(size_t)row * ldc + col] = f2bf(acc[m][n][r]);
        }
  }
}

// 128x128-tile bf16 MFMA GEMM (legacy path for non-pre tiers / R<4096).
template<int BF32, int CMODE>
__global__ __launch_bounds__(256) void mfma_gemm(
    const unsigned short* __restrict__ Abf, const void* __restrict__ Bv,
    void* __restrict__ Cv, float* __restrict__ colsum,
    int K, int lda, int ldb, int ldc)
{
  __shared__ unsigned short As[128 * 32];
  __shared__ unsigned short Bs[128 * 32];
  const int t = threadIdx.x;
  const int lane = t & 63, wid = t >> 6;
  const int wm = (wid >> 1) * 64, wn = (wid & 1) * 64;
  const int i0 = blockIdx.y * 128, j0 = blockIdx.x * 128;
  const int lr = lane & 15, lq = lane >> 4;

  f32x4 acc[4][4];
  #pragma unroll
  for (int a = 0; a < 4; a++)
    #pragma unroll
    for (int b = 0; b < 4; b++) acc[a][b] = (f32x4){0.f, 0.f, 0.f, 0.f};

  for (int k0 = 0; k0 < K; k0 += 32) {
    #pragma unroll
    for (int u = 0; u < 2; u++) {
      int vid = u * 256 + t;
      int row = vid >> 2, kq = (vid & 3) * 8;
      dma16(Abf + (size_t)(i0 + row) * lda + k0 + kq,
            &As[(u * 256 + wid * 64) * 8]);
    }
    if (BF32 == 0) {
      #pragma unroll
      for (int u = 0; u < 2; u++) {
        int vid = u * 256 + t;
        int row = vid >> 2, kq = (vid & 3) * 8;
        dma16((const unsigned short*)Bv + (size_t)(j0 + row) * ldb + k0 + kq,
              &Bs[(u * 256 + wid * 64) * 8]);
      }
    } else {
      #pragma unroll
      for (int u = 0; u < 2; u++) {
        int vid = u * 256 + t;
        int row = vid >> 2, kq = (vid & 3) * 8;
        const float* s = (const float*)Bv + (size_t)(j0 + row) * ldb + k0 + kq;
        float4 f0 = *(const float4*)s;
        float4 f1 = *(const float4*)(s + 4);
        union { unsigned short h[8]; int4 v; } pk;
        pk.h[0] = f2bf(f0.x); pk.h[1] = f2bf(f0.y);
        pk.h[2] = f2bf(f0.z); pk.h[3] = f2bf(f0.w);
        pk.h[4] = f2bf(f1.x); pk.h[5] = f2bf(f1.y);
        pk.h[6] = f2bf(f1.z); pk.h[7] = f2bf(f1.w);
        *(int4*)&Bs[(size_t)vid * 8] = pk.v;
      }
    }
    __syncthreads();

    short8 af[4], bfr[4];
    #pragma unroll
    for (int tm = 0; tm < 4; tm++)
      af[tm] = *(const short8*)&As[(wm + tm * 16 + lr) * 32 + lq * 8];
    #pragma unroll
    for (int tn = 0; tn < 4; tn++)
      bfr[tn] = *(const short8*)&Bs[(wn + tn * 16 + lr) * 32 + lq * 8];

    #pragma unroll
    for (int tm = 0; tm < 4; tm++)
      #pragma unroll
      for (int tn = 0; tn < 4; tn++)
        acc[tm][tn] = __builtin_amdgcn_mfma_f32_16x16x32_bf16(
            af[tm], bfr[tn], acc[tm][tn], 0, 0, 0);
    __syncthreads();
  }

  if (CMODE == 2) {
    #pragma unroll
    for (int tn = 0; tn < 4; tn++) {
      float s = 0.f;
      #pragma unroll
      for (int tm = 0; tm < 4; tm++)
        #pragma unroll
        for (int r = 0; r < 4; r++) s += tanhf(acc[tm][tn][r]);
      s += __shfl_xor(s, 16);
      s += __shfl_xor(s, 32);
      if (lq == 0) atomicAdd(&colsum[j0 + wn + tn * 16 + lr], s);
    }
  } else {
    #pragma unroll
    for (int tm = 0; tm < 4; tm++)
      #pragma unroll
      for (int tn = 0; tn < 4; tn++)
        #pragma unroll
        for (int r = 0; r < 4; r++) {
          int row = i0 + wm + tm * 16 + lq * 4 + r;
          int col = j0 + wn + tn * 16 + lr;
          if (CMODE == 0)
            ((float*)Cv)[(size_t)row * ldc + col] = acc[tm][tn][r];
          else
            ((unsigned short*)Cv)[(size_t)row * ldc + col] = f2bf(acc[tm][tn][r]);
        }
  }
}

// Tt_bf[key][l] = bf16(T[l][key]); T [2048][4096] fp32.
__global__ __launch_bounds__(256) void transpose_bf16(
    const float* __restrict__ T, unsigned short* __restrict__ Tt)
{
  __shared__ float tile[64][65];
  const int tx = threadIdx.x & 63;
  const int ty = threadIdx.x >> 6;
  const int k0 = blockIdx.x * 64;
  const int l0 = blockIdx.y * 64;
  #pragma unroll
  for (int u = 0; u < 16; u++) {
    int row = ty * 16 + u;
    tile[row][tx] = T[(size_t)(l0 + row) * 4096 + k0 + tx];
  }
  __syncthreads();
  #pragma unroll
  for (int u = 0; u < 16; u++) {
    int row = ty * 16 + u;
    Tt[(size_t)(k0 + row) * 2048 + l0 + tx] = f2bf(tile[tx][row]);
  }
}

// out[i] = bf16(in[i]), 8 elements/thread, packed 16B stores.
__global__ __launch_bounds__(256) void cvt_bf16(
    const float* __restrict__ in, unsigned short* __restrict__ out, int n8)
{
  int i = blockIdx.x * 256 + threadIdx.x;
  if (i >= n8) return;
  float4 f0 = ((const float4*)in)[(size_t)i * 2];
  float4 f1 = ((const float4*)in)[(size_t)i * 2 + 1];
  union { unsigned short h[8]; int4 v; } pk;
  pk.h[0] = f2bf(f0.x); pk.h[1] = f2bf(f0.y);
  pk.h[2] = f2bf(f0.z); pk.h[3] = f2bf(f0.w);
  pk.h[4] = f2bf(f1.x); pk.h[5] = f2bf(f1.y);
  pk.h[6] = f2bf(f1.z); pk.h[7] = f2bf(f1.w);
  ((int4*)out)[i] = pk.v;
}

// Row softmax over 4096 fp32, writes bf16 IN PLACE at row start.
__global__ __launch_bounds__(256) void softmax_bf16(float* __restrict__ S)
{
  float* p = S + (size_t)blockIdx.x * 4096;
  const int tid = threadIdx.x;
  float4 v[4];
  #pragma unroll
  for (int u = 0; u < 4; u++) v[u] = ((const float4*)p)[tid * 4 + u];

  float m = -3.4e38f;
  #pragma unroll
  for (int u = 0; u < 4; u++)
    m = fmaxf(m, fmaxf(fmaxf(v[u].x, v[u].y), fmaxf(v[u].z, v[u].w)));
  #pragma unroll
  for (int off = 32; off > 0; off >>= 1) m = fmaxf(m, __shfl_down(m, off, 64));
  __shared__ float redm[4];
  if ((tid & 63) == 0) redm[tid >> 6] = m;
  __syncthreads();
  m = fmaxf(fmaxf(redm[0], redm[1]), fmaxf(redm[2], redm[3]));

  float s = 0.f;
  #pragma unroll
  for (int u = 0; u < 4; u++) {
    v[u].x = __expf(v[u].x - m); v[u].y = __expf(v[u].y - m);
    v[u].z = __expf(v[u].z - m); v[u].w = __expf(v[u].w - m);
    s += v[u].x + v[u].y + v[u].z + v[u].w;
  }
  #pragma unroll
  for (int off = 32; off > 0; off >>= 1) s += __shfl_down(s, off, 64);
  __shared__ float reds[4];
  if ((tid & 63) == 0) reds[tid >> 6] = s;
  __syncthreads();
  s = reds[0] + reds[1] + reds[2] + reds[3];
  const float inv = 1.f / s;

  unsigned short* a = (unsigned short*)p;
  #pragma unroll
  for (int h = 0; h < 2; h++) {
    union { unsigned short u[8]; int4 q; } pk;
    #pragma unroll
    for (int j = 0; j < 2; j++) {
      float4 w = v[h * 2 + j];
      pk.u[j * 4 + 0] = f2bf(w.x * inv); pk.u[j * 4 + 1] = f2bf(w.y * inv);
      pk.u[j * 4 + 2] = f2bf(w.z * inv); pk.u[j * 4 + 3] = f2bf(w.w * inv);
    }
    ((int4*)a)[tid * 2 + h] = pk.q;
  }
}

__global__ void zero_k(float* p, int n)
{
  int i = blockIdx.x * 256 + threadIdx.x;
  if (i < n) p[i] = 0.f;
}

// scores /= max; softmax; -> FP32 out (2048).
__global__ __launch_bounds__(256) void finalize_k(const float* __restrict__ scores,
                                                  float* __restrict__ out)
{
  const int tid = threadIdx.x;
  float s[8];
  #pragma unroll
  for (int u = 0; u < 8; u++) s[u] = scores[tid + u * 256];

  __shared__ float red[4];

  float m = -3.4e38f;
  #pragma unroll
  for (int u = 0; u < 8; u++) m = fmaxf(m, s[u]);
  #pragma unroll
  for (int off = 32; off > 0; off >>= 1) m = fmaxf(m, __shfl_down(m, off, 64));
  if ((tid & 63) == 0) red[tid >> 6] = m;
  __syncthreads();
  m = fmaxf(fmaxf(red[0], red[1]), fmaxf(red[2], red[3]));
  __syncthreads();

  const float inv1 = 1.f / m;
  #pragma unroll
  for (int u = 0; u < 8; u++) s[u] *= inv1;

  float m2 = -3.4e38f;
  #pragma unroll
  for (int u = 0; u < 8; u++) m2 = fmaxf(m2, s[u]);
  #pragma unroll
  for (int off = 32; off > 0; off >>= 1) m2 = fmaxf(m2, __shfl_down(m2, off, 64));
  if ((tid & 63) == 0) red[tid >> 6] = m2;
  __syncthreads();
  m2 = fmaxf(fmaxf(red[0], red[1]), fmaxf(red[2], red[3]));
  __syncthreads();

  float sum = 0.f;
  #pragma unroll
  for (int u = 0; u < 8; u++) { s[u] = expf(s[u] - m2); sum += s[u]; }
  #pragma unroll
  for (int off = 32; off > 0; off >>= 1) sum += __shfl_down(sum, off, 64);
  if ((tid & 63) == 0) red[tid >> 6] = sum;
  __syncthreads();
  sum = red[0] + red[1] + red[2] + red[3];

  const float invs = 1.f / sum;
  #pragma unroll
  for (int u = 0; u < 8; u++)
    out[tid + u * 256] = s[u] * invs;
}

extern "C" void kernel_launch(void* const* d_in, const int* in_sizes, int n_in,
                              void* d_out, int out_size, void* d_ws, size_t ws_size,
                              hipStream_t stream)
{
  const float* T    = (const float*)d_in[0];   // [2048][4096]
  const float* Win  = (const float*)d_in[1];   // [2048][2048] 'ml'
  const float* Wout = (const float*)d_in[2];   // [2048][4096] 'lc'
  float* out = (float*)d_out;

  const size_t FIX1 = 92274688ull + 16384;
  int R = 1024; bool pre = false;
  if      (ws_size >= FIX1 + (size_t)4096 * 16384) { pre = true; R = 4096; }
  else if (ws_size >= FIX1 + (size_t)2048 * 16384) { pre = true; R = 2048; }
  else if (ws_size >= FIX1 + (size_t)1024 * 16384) { pre = true; R = 1024; }

  unsigned short* Tt = (unsigned short*)d_ws;

  if (pre) {
    unsigned short* Tb    = Tt + (size_t)4096 * 2048;
    unsigned short* Winb  = Tb + (size_t)2048 * 4096;
    unsigned short* Woutb = Winb + (size_t)2048 * 2048;
    unsigned short* comb  = Woutb + (size_t)2048 * 4096;
    float* S      = (float*)(comb + (size_t)4096 * 4096);
    float* scores = S + (size_t)R * 4096;

    zero_k<<<8, 256, 0, stream>>>(scores, 2048);
    transpose_bf16<<<dim3(64, 32), 256, 0, stream>>>(T, Tt);
    cvt_bf16<<<4096, 256, 0, stream>>>(T, Tb, 1048576);
    cvt_bf16<<<2048, 256, 0, stream>>>(Win, Winb, 524288);
    cvt_bf16<<<4096, 256, 0, stream>>>(Wout, Woutb, 1048576);

    // GEMM1: Q -> comb[:,2048:]  (M=4096,N=2048,K=2048 -> 16x16 full fill)
    gemm_n128<1><<<256, 512, 0, stream>>>(
        Tt, Winb, comb + 2048, nullptr, 2048, 2048, 2048, 4096);
    for (int c = 0; c < 4096 / R; c++) {
      const size_t d0 = (size_t)c * R;
      if (R == 4096) {
        // GEMM2 (4096x4096x2048): 256^2 counted-vmcnt template
        gemm256<<<256, 512, 0, stream>>>(
            comb + 2048, Tt, S, 2048, 4096, 2048, 4096);
      } else {
        mfma_gemm<0, 0><<<dim3(32, R / 128), 256, 0, stream>>>(
            comb + d0 * 4096 + 2048, Tt, S, nullptr, 2048, 4096, 2048, 4096);
      }
      softmax_bf16<<<R, 256, 0, stream>>>(S);
      if (R == 4096) {
        // GEMM3 (4096x2048x4096): BM256xBN128 template
        gemm_n128<1><<<256, 512, 0, stream>>>(
            (unsigned short*)S, Tb, comb, nullptr, 4096, 8192, 4096, 4096);
      } else {
        mfma_gemm<0, 1><<<dim3(16, R / 128), 256, 0, stream>>>(
            (unsigned short*)S, Tb, comb + d0 * 4096, nullptr, 4096, 8192, 4096, 4096);
      }
    }
    // GEMM4 (4096x2048x4096, tanh colsum): BM256xBN128 template
    gemm_n128<2><<<256, 512, 0, stream>>>(
        comb, Woutb, nullptr, scores, 4096, 4096, 4096, 4096);
    finalize_k<<<1, 256, 0, stream>>>(scores, out);
  } else {
    // tier0: r12 layout (67,117,056 B proven to fit), inline cvt for fp32 B.
    unsigned short* comb = Tt + (size_t)4096 * 2048;
    float* S      = (float*)(comb + (size_t)4096 * 4096);
    float* scores = S + (size_t)1024 * 4096;

    zero_k<<<8, 256, 0, stream>>>(scores, 2048);
    transpose_bf16<<<dim3(64, 32), 256, 0, stream>>>(T, Tt);

    mfma_gemm<1, 1><<<dim3(16, 32), 256, 0, stream>>>(
        Tt, Win, comb + 2048, nullptr, 2048, 2048, 2048, 4096);
    for (int c = 0; c < 4; c++) {
      const size_t d0 = (size_t)c * 1024;
      mfma_gemm<0, 0><<<dim3(32, 8), 256, 0, stream>>>(
          comb + d0 * 4096 + 2048, Tt, S, nullptr, 2048, 4096, 2048, 4096);
      softmax_bf16<<<1024, 256, 0, stream>>>(S);
      mfma_gemm<1, 1><<<dim3(16, 8), 256, 0, stream>>>(
          (unsigned short*)S, T, comb + d0 * 4096, nullptr, 4096, 8192, 4096, 4096);
    }
    mfma_gemm<1, 2><<<dim3(16, 32), 256, 0, stream>>>(
        comb, Wout, nullptr, scores, 4096, 4096, 4096, 4096);
    finalize_k<<<1, 256, 0, stream>>>(scores, out);
  }
}

// Round 4
// 362.230 us; speedup vs baseline: 1.2857x; 1.1188x over previous
//
#include <hip/hip_runtime.h>
#include <hip/hip_bf16.h>
#include <math.h>

// BS=1, L=2048, D=4096. r15 measured 405.3us.
// r16: gemm_n128 -> TRIPLE-buffered K-pipeline (3 x 48KiB = 144KiB LDS).
// Stage tile kt+2 while computing kt: issue-to-wait distance = 2 K-tiles
// (~1000+ cyc, covers HBM latency; dbuf's 2-phase distance did not).
// Sync per 32-MFMA K-tile drops from 4 barriers + 2 waits to 1 barrier +
// 1 vmcnt(6) wait. Ledger: entry invariant 6 in flight (tile kt+1); +6
// issued (kt+2); vmcnt(6) at tile end drains kt+1 exactly. WAR safe: kt+2's
// DMA hits buffer (kt-1)%3, fully read before the end-of-(kt-1) barrier.
// r15 counters: gemm_n128 87us, MfmaUtil 31%, bank-conflict 0, occ 21% ->
// latency/sync-bound, not LDS- or HBM-bound.

typedef __attribute__((ext_vector_type(8))) short short8;
typedef __attribute__((ext_vector_type(4))) float f32x4;

__device__ __forceinline__ unsigned short f2bf(float f) {
  unsigned u = __float_as_uint(f);
  return (unsigned short)((u + 0x7FFF + ((u >> 16) & 1)) >> 16);  // RNE
}

typedef const __attribute__((address_space(1))) unsigned int* gas_t;
typedef __attribute__((address_space(3))) unsigned int* las_t;
__device__ __forceinline__ void dma16(const unsigned short* g, unsigned short* l)
{
  __builtin_amdgcn_global_load_lds((gas_t)(const void*)g, (las_t)(void*)l,
                                   16, 0, 0);
}

// ---------------------------------------------------------------------------
// 256x256-tile, BK=64, counted-vmcnt 4-phase GEMM (C fp32 out). GEMM2 only.
// ---------------------------------------------------------------------------
__global__ __launch_bounds__(512, 2) void gemm256(
    const unsigned short* __restrict__ A, const unsigned short* __restrict__ B,
    float* __restrict__ C, int K, int lda, int ldb, int ldc)
{
  __shared__ unsigned short sm[2][2][256 * 64];
  const int t = threadIdx.x;
  const int lane = t & 63;
  const int wid = t >> 6;
  const int wr = wid >> 2;
  const int wc = wid & 3;
  const int lr = lane & 15, lq = lane >> 4;

  int bx, by;
  {
    int wg = blockIdx.x;
    int x = wg & 7, s = wg >> 3;
    by = (x & 3) * 4 + (s >> 3);
    bx = (x >> 2) * 8 + (s & 7);
  }
  const int i0 = by * 256, j0 = bx * 256;

  const int r_ = t >> 3;
  const int ss_ = ((t & 7) ^ (r_ & 7)) * 8;

  auto issue = [&](int buf, int c, int k0) {
    const unsigned short* M;
    int ld, r0;
    if (c < 4) { M = A; ld = lda; r0 = i0 + (c & 3) * 64; }
    else       { M = B; ld = ldb; r0 = j0 + (c & 3) * 64; }
    unsigned short* lb = &sm[buf][c >> 2][(c & 3) * 4096];
    dma16(M + (size_t)(r0 + r_) * ld + k0 + ss_, lb + wid * 512);
  };

  auto frag = [&](const unsigned short* mat, int row, int kh) -> short8 {
    int lb = row * 128 + kh * 64 + (lq << 4);
    int pb = lb ^ ((row & 7) << 4);
    return *(const short8*)((const char*)mat + pb);
  };

  f32x4 acc[8][4];
  #pragma unroll
  for (int a = 0; a < 8; a++)
    #pragma unroll
    for (int b = 0; b < 4; b++) acc[a][b] = (f32x4){0.f, 0.f, 0.f, 0.f};

  issue(0, 0, 0); issue(0, 2, 0);
  issue(0, 4, 0); issue(0, 5, 0);
  issue(0, 6, 0); issue(0, 7, 0);
  issue(0, 1, 0); issue(0, 3, 0);
  asm volatile("s_waitcnt vmcnt(2)" ::: "memory");
  __builtin_amdgcn_s_barrier();

  const int NT = K >> 6;
  for (int kt = 0; kt < NT; kt++) {
    const int cur = kt & 1;
    const unsigned short* As = sm[cur][0];
    const unsigned short* Bs = sm[cur][1];
    const int kn = (kt + 1) << 6;
    const bool st = (kt + 1 < NT);
    short8 bfr[4][2];

    #pragma unroll
    for (int p = 0; p < 4; p++) {
      short8 a0k0 = frag(As, wr * 128 + (p * 2 + 0) * 16 + lr, 0);
      short8 a0k1 = frag(As, wr * 128 + (p * 2 + 0) * 16 + lr, 1);
      short8 a1k0 = frag(As, wr * 128 + (p * 2 + 1) * 16 + lr, 0);
      short8 a1k1 = frag(As, wr * 128 + (p * 2 + 1) * 16 + lr, 1);
      if (p == 0) {
        #pragma unroll
        for (int nf = 0; nf < 4; nf++) {
          bfr[nf][0] = frag(Bs, wc * 64 + nf * 16 + lr, 0);
          bfr[nf][1] = frag(Bs, wc * 64 + nf * 16 + lr, 1);
        }
      }
      if (st) {
        if (p == 0) { issue(cur ^ 1, 0, kn); issue(cur ^ 1, 2, kn); }
        if (p == 1) { issue(cur ^ 1, 4, kn); issue(cur ^ 1, 5, kn); }
        if (p == 2) { issue(cur ^ 1, 6, kn); issue(cur ^ 1, 7, kn); }
        if (p == 3) { issue(cur ^ 1, 1, kn); issue(cur ^ 1, 3, kn); }
      }
      asm volatile("" ::: "memory");
      __builtin_amdgcn_s_barrier();
      __builtin_amdgcn_s_setprio(1);
      #pragma unroll
      for (int nf = 0; nf < 4; nf++) {
        acc[p * 2 + 0][nf] = __builtin_amdgcn_mfma_f32_16x16x32_bf16(
            a0k0, bfr[nf][0], acc[p * 2 + 0][nf], 0, 0, 0);
        acc[p * 2 + 0][nf] = __builtin_amdgcn_mfma_f32_16x16x32_bf16(
            a0k1, bfr[nf][1], acc[p * 2 + 0][nf], 0, 0, 0);
        acc[p * 2 + 1][nf] = __builtin_amdgcn_mfma_f32_16x16x32_bf16(
            a1k0, bfr[nf][0], acc[p * 2 + 1][nf], 0, 0, 0);
        acc[p * 2 + 1][nf] = __builtin_amdgcn_mfma_f32_16x16x32_bf16(
            a1k1, bfr[nf][1], acc[p * 2 + 1][nf], 0, 0, 0);
      }
      __builtin_amdgcn_s_setprio(0);
      if (p == 1) {
        if (st) asm volatile("s_waitcnt vmcnt(4)" ::: "memory");
        else    asm volatile("s_waitcnt vmcnt(0)" ::: "memory");
      }
      if (p == 3 && st) asm volatile("s_waitcnt vmcnt(2)" ::: "memory");
      asm volatile("" ::: "memory");
      __builtin_amdgcn_s_barrier();
    }
  }

  #pragma unroll
  for (int mf = 0; mf < 8; mf++)
    #pragma unroll
    for (int nf = 0; nf < 4; nf++)
      #pragma unroll
      for (int r = 0; r < 4; r++) {
        int row = i0 + wr * 128 + mf * 16 + lq * 4 + r;
        int col = j0 + wc * 64 + nf * 16 + lr;
        C[(size_t)row * ldc + col] = acc[mf][nf][r];
      }
}

// ---------------------------------------------------------------------------
// r16: BM=256 x BN=128, BK=64, TRIPLE-buffered counted-vmcnt GEMM.
// Grid must be (M/256)*(N/128) = 256 blocks. LDS 144KiB -> 1 block/CU.
// C[i][j] = sum_k A[i][k]*B[j][k], both bf16 k-major.
// CMODE 1: C bf16 out. CMODE 2: colsum[j] += sum_i tanh(acc).
// Pipeline: compute tile kt from buf kt%3 while tile kt+1 is landed/landing
// and tile kt+2 is being issued. One vmcnt(6)+barrier per K-tile.
// ---------------------------------------------------------------------------
template<int CMODE>
__global__ __launch_bounds__(512, 2) void gemm_n128(
    const unsigned short* __restrict__ A, const unsigned short* __restrict__ B,
    void* __restrict__ Cv, float* __restrict__ colsum,
    int K, int lda, int ldb, int ldc)
{
  // chunks: c0..c3 = A rows c*64 (32KiB); c4,c5 = B rows (c-4)*64 (16KiB)
  __shared__ unsigned short sm[3][384 * 64];   // 3 x 48KiB
  const int t = threadIdx.x;
  const int lane = t & 63, wid = t >> 6;
  const int wr = wid >> 2;          // 0..1 (M half: 128 rows)
  const int wc = wid & 3;           // 0..3 (N quarter: 32 cols)
  const int lr = lane & 15, lq = lane >> 4;

  int bx, by;
  {
    int wg = blockIdx.x;
    int x = wg & 7, s = wg >> 3;
    by = (x & 3) * 4 + (s >> 3);
    bx = (x >> 2) * 8 + (s & 7);
  }
  const int i0 = by * 256, j0 = bx * 128;

  const int r_ = t >> 3;                       // row within chunk (0..63)
  const int ss_ = ((t & 7) ^ (r_ & 7)) * 8;    // swizzled source col (elems)

  auto issue = [&](int buf, int c, int k0) {
    const unsigned short* M;
    int ld, r0;
    if (c < 4) { M = A; ld = lda; r0 = i0 + c * 64; }
    else       { M = B; ld = ldb; r0 = j0 + (c - 4) * 64; }
    unsigned short* lb = &sm[buf][c * 4096];
    dma16(M + (size_t)(r0 + r_) * ld + k0 + ss_, lb + wid * 512);
  };

  auto frag = [&](const unsigned short* mat, int row, int kh) -> short8 {
    int lb = row * 128 + kh * 64 + (lq << 4);
    int pb = lb ^ ((row & 7) << 4);
    return *(const short8*)((const char*)mat + pb);
  };

  f32x4 acc[8][2];
  #pragma unroll
  for (int a = 0; a < 8; a++)
    #pragma unroll
    for (int b = 0; b < 2; b++) acc[a][b] = (f32x4){0.f, 0.f, 0.f, 0.f};

  // Prologue: fully issue tiles 0 and 1; wait for tile 0 (6 left in flight).
  #pragma unroll
  for (int c = 0; c < 6; c++) issue(0, c, 0);
  #pragma unroll
  for (int c = 0; c < 6; c++) issue(1, c, 64);
  asm volatile("s_waitcnt vmcnt(6)" ::: "memory");
  __builtin_amdgcn_s_barrier();

  const int NT = K >> 6;
  int cur = 0;
  for (int kt = 0; kt < NT; kt++) {
    const unsigned short* As = sm[cur];
    const unsigned short* Bs = sm[cur] + 256 * 64;   // B rows 0..127
    const int b2 = (cur + 2 >= 3) ? cur - 1 : cur + 2;   // (cur+2)%3
    const int kn = (kt + 2) << 6;
    const bool st = (kt + 2 < NT);

    short8 af[4][2], bfr[2][2];
    // ---- q0: A rows wr*128 + (0..3)*16, all B ----
    #pragma unroll
    for (int m = 0; m < 4; m++) {
      af[m][0] = frag(As, wr * 128 + m * 16 + lr, 0);
      af[m][1] = frag(As, wr * 128 + m * 16 + lr, 1);
    }
    #pragma unroll
    for (int n = 0; n < 2; n++) {
      bfr[n][0] = frag(Bs, wc * 32 + n * 16 + lr, 0);
      bfr[n][1] = frag(Bs, wc * 32 + n * 16 + lr, 1);
    }
    if (st) {
      issue(b2, 0, kn); issue(b2, 2, kn);
      issue(b2, 4, kn); issue(b2, 5, kn);
    }
    __builtin_amdgcn_s_setprio(1);
    #pragma unroll
    for (int m = 0; m < 4; m++)
      #pragma unroll
      for (int n = 0; n < 2; n++) {
        acc[m][n] = __builtin_amdgcn_mfma_f32_16x16x32_bf16(
            af[m][0], bfr[n][0], acc[m][n], 0, 0, 0);
        acc[m][n] = __builtin_amdgcn_mfma_f32_16x16x32_bf16(
            af[m][1], bfr[n][1], acc[m][n], 0, 0, 0);
      }
    __builtin_amdgcn_s_setprio(0);

    // ---- q1: A rows wr*128 + (4..7)*16 ----
    #pragma unroll
    for (int m = 0; m < 4; m++) {
      af[m][0] = frag(As, wr * 128 + (4 + m) * 16 + lr, 0);
      af[m][1] = frag(As, wr * 128 + (4 + m) * 16 + lr, 1);
    }
    if (st) { issue(b2, 1, kn); issue(b2, 3, kn); }
    __builtin_amdgcn_s_setprio(1);
    #pragma unroll
    for (int m = 0; m < 4; m++)
      #pragma unroll
      for (int n = 0; n < 2; n++) {
        acc[4 + m][n] = __builtin_amdgcn_mfma_f32_16x16x32_bf16(
            af[m][0], bfr[n][0], acc[4 + m][n], 0, 0, 0);
        acc[4 + m][n] = __builtin_amdgcn_mfma_f32_16x16x32_bf16(
            af[m][1], bfr[n][1], acc[4 + m][n], 0, 0, 0);
      }
    __builtin_amdgcn_s_setprio(0);

    // ---- end-of-tile: ensure tile kt+1 fully landed before next iter ----
    if (kt + 1 < NT) {
      if (st) asm volatile("s_waitcnt vmcnt(6)" ::: "memory");
      else    asm volatile("s_waitcnt vmcnt(0)" ::: "memory");
      __builtin_amdgcn_s_barrier();
    }
    cur = (cur + 1 == 3) ? 0 : cur + 1;
  }

  if (CMODE == 2) {
    // C/D layout: col=lane&15, row=lq*4+reg.
    #pragma unroll
    for (int n = 0; n < 2; n++) {
      float s = 0.f;
      #pragma unroll
      for (int m = 0; m < 8; m++)
        #pragma unroll
        for (int r = 0; r < 4; r++) s += tanhf(acc[m][n][r]);
      s += __shfl_xor(s, 16);
      s += __shfl_xor(s, 32);
      if (lq == 0) atomicAdd(&colsum[j0 + wc * 32 + n * 16 + lr], s);
    }
  } else {
    #pragma unroll
    for (int m = 0; m < 8; m++)
      #pragma unroll
      for (int n = 0; n < 2; n++)
        #pragma unroll
        for (int r = 0; r < 4; r++) {
          int row = i0 + wr * 128 + m * 16 + lq * 4 + r;
          int col = j0 + wc * 32 + n * 16 + lr;
          ((unsigned short*)Cv)[(size_t)row * ldc + col] = f2bf(acc[m][n][r]);
        }
  }
}

// 128x128-tile bf16 MFMA GEMM (legacy path for non-pre tiers / R<4096).
template<int BF32, int CMODE>
__global__ __launch_bounds__(256) void mfma_gemm(
    const unsigned short* __restrict__ Abf, const void* __restrict__ Bv,
    void* __restrict__ Cv, float* __restrict__ colsum,
    int K, int lda, int ldb, int ldc)
{
  __shared__ unsigned short As[128 * 32];
  __shared__ unsigned short Bs[128 * 32];
  const int t = threadIdx.x;
  const int lane = t & 63, wid = t >> 6;
  const int wm = (wid >> 1) * 64, wn = (wid & 1) * 64;
  const int i0 = blockIdx.y * 128, j0 = blockIdx.x * 128;
  const int lr = lane & 15, lq = lane >> 4;

  f32x4 acc[4][4];
  #pragma unroll
  for (int a = 0; a < 4; a++)
    #pragma unroll
    for (int b = 0; b < 4; b++) acc[a][b] = (f32x4){0.f, 0.f, 0.f, 0.f};

  for (int k0 = 0; k0 < K; k0 += 32) {
    #pragma unroll
    for (int u = 0; u < 2; u++) {
      int vid = u * 256 + t;
      int row = vid >> 2, kq = (vid & 3) * 8;
      dma16(Abf + (size_t)(i0 + row) * lda + k0 + kq,
            &As[(u * 256 + wid * 64) * 8]);
    }
    if (BF32 == 0) {
      #pragma unroll
      for (int u = 0; u < 2; u++) {
        int vid = u * 256 + t;
        int row = vid >> 2, kq = (vid & 3) * 8;
        dma16((const unsigned short*)Bv + (size_t)(j0 + row) * ldb + k0 + kq,
              &Bs[(u * 256 + wid * 64) * 8]);
      }
    } else {
      #pragma unroll
      for (int u = 0; u < 2; u++) {
        int vid = u * 256 + t;
        int row = vid >> 2, kq = (vid & 3) * 8;
        const float* s = (const float*)Bv + (size_t)(j0 + row) * ldb + k0 + kq;
        float4 f0 = *(const float4*)s;
        float4 f1 = *(const float4*)(s + 4);
        union { unsigned short h[8]; int4 v; } pk;
        pk.h[0] = f2bf(f0.x); pk.h[1] = f2bf(f0.y);
        pk.h[2] = f2bf(f0.z); pk.h[3] = f2bf(f0.w);
        pk.h[4] = f2bf(f1.x); pk.h[5] = f2bf(f1.y);
        pk.h[6] = f2bf(f1.z); pk.h[7] = f2bf(f1.w);
        *(int4*)&Bs[(size_t)vid * 8] = pk.v;
      }
    }
    __syncthreads();

    short8 af[4], bfr[4];
    #pragma unroll
    for (int tm = 0; tm < 4; tm++)
      af[tm] = *(const short8*)&As[(wm + tm * 16 + lr) * 32 + lq * 8];
    #pragma unroll
    for (int tn = 0; tn < 4; tn++)
      bfr[tn] = *(const short8*)&Bs[(wn + tn * 16 + lr) * 32 + lq * 8];

    #pragma unroll
    for (int tm = 0; tm < 4; tm++)
      #pragma unroll
      for (int tn = 0; tn < 4; tn++)
        acc[tm][tn] = __builtin_amdgcn_mfma_f32_16x16x32_bf16(
            af[tm], bfr[tn], acc[tm][tn], 0, 0, 0);
    __syncthreads();
  }

  if (CMODE == 2) {
    #pragma unroll
    for (int tn = 0; tn < 4; tn++) {
      float s = 0.f;
      #pragma unroll
      for (int tm = 0; tm < 4; tm++)
        #pragma unroll
        for (int r = 0; r < 4; r++) s += tanhf(acc[tm][tn][r]);
      s += __shfl_xor(s, 16);
      s += __shfl_xor(s, 32);
      if (lq == 0) atomicAdd(&colsum[j0 + wn + tn * 16 + lr], s);
    }
  } else {
    #pragma unroll
    for (int tm = 0; tm < 4; tm++)
      #pragma unroll
      for (int tn = 0; tn < 4; tn++)
        #pragma unroll
        for (int r = 0; r < 4; r++) {
          int row = i0 + wm + tm * 16 + lq * 4 + r;
          int col = j0 + wn + tn * 16 + lr;
          if (CMODE == 0)
            ((float*)Cv)[(size_t)row * ldc + col] = acc[tm][tn][r];
          else
            ((unsigned short*)Cv)[(size_t)row * ldc + col] = f2bf(acc[tm][tn][r]);
        }
  }
}

// Tt_bf[key][l] = bf16(T[l][key]); T [2048][4096] fp32.
__global__ __launch_bounds__(256) void transpose_bf16(
    const float* __restrict__ T, unsigned short* __restrict__ Tt)
{
  __shared__ float tile[64][65];
  const int tx = threadIdx.x & 63;
  const int ty = threadIdx.x >> 6;
  const int k0 = blockIdx.x * 64;
  const int l0 = blockIdx.y * 64;
  #pragma unroll
  for (int u = 0; u < 16; u++) {
    int row = ty * 16 + u;
    tile[row][tx] = T[(size_t)(l0 + row) * 4096 + k0 + tx];
  }
  __syncthreads();
  #pragma unroll
  for (int u = 0; u < 16; u++) {
    int row = ty * 16 + u;
    Tt[(size_t)(k0 + row) * 2048 + l0 + tx] = f2bf(tile[tx][row]);
  }
}

// out[i] = bf16(in[i]), 8 elements/thread, packed 16B stores.
__global__ __launch_bounds__(256) void cvt_bf16(
    const float* __restrict__ in, unsigned short* __restrict__ out, int n8)
{
  int i = blockIdx.x * 256 + threadIdx.x;
  if (i >= n8) return;
  float4 f0 = ((const float4*)in)[(size_t)i * 2];
  float4 f1 = ((const float4*)in)[(size_t)i * 2 + 1];
  union { unsigned short h[8]; int4 v; } pk;
  pk.h[0] = f2bf(f0.x); pk.h[1] = f2bf(f0.y);
  pk.h[2] = f2bf(f0.z); pk.h[3] = f2bf(f0.w);
  pk.h[4] = f2bf(f1.x); pk.h[5] = f2bf(f1.y);
  pk.h[6] = f2bf(f1.z); pk.h[7] = f2bf(f1.w);
  ((int4*)out)[i] = pk.v;
}

// Row softmax over 4096 fp32, writes bf16 IN PLACE at row start.
__global__ __launch_bounds__(256) void softmax_bf16(float* __restrict__ S)
{
  float* p = S + (size_t)blockIdx.x * 4096;
  const int tid = threadIdx.x;
  float4 v[4];
  #pragma unroll
  for (int u = 0; u < 4; u++) v[u] = ((const float4*)p)[tid * 4 + u];

  float m = -3.4e38f;
  #pragma unroll
  for (int u = 0; u < 4; u++)
    m = fmaxf(m, fmaxf(fmaxf(v[u].x, v[u].y), fmaxf(v[u].z, v[u].w)));
  #pragma unroll
  for (int off = 32; off > 0; off >>= 1) m = fmaxf(m, __shfl_down(m, off, 64));
  __shared__ float redm[4];
  if ((tid & 63) == 0) redm[tid >> 6] = m;
  __syncthreads();
  m = fmaxf(fmaxf(redm[0], redm[1]), fmaxf(redm[2], redm[3]));

  float s = 0.f;
  #pragma unroll
  for (int u = 0; u < 4; u++) {
    v[u].x = __expf(v[u].x - m); v[u].y = __expf(v[u].y - m);
    v[u].z = __expf(v[u].z - m); v[u].w = __expf(v[u].w - m);
    s += v[u].x + v[u].y + v[u].z + v[u].w;
  }
  #pragma unroll
  for (int off = 32; off > 0; off >>= 1) s += __shfl_down(s, off, 64);
  __shared__ float reds[4];
  if ((tid & 63) == 0) reds[tid >> 6] = s;
  __syncthreads();
  s = reds[0] + reds[1] + reds[2] + reds[3];
  const float inv = 1.f / s;

  unsigned short* a = (unsigned short*)p;
  #pragma unroll
  for (int h = 0; h < 2; h++) {
    union { unsigned short u[8]; int4 q; } pk;
    #pragma unroll
    for (int j = 0; j < 2; j++) {
      float4 w = v[h * 2 + j];
      pk.u[j * 4 + 0] = f2bf(w.x * inv); pk.u[j * 4 + 1] = f2bf(w.y * inv);
      pk.u[j * 4 + 2] = f2bf(w.z * inv); pk.u[j * 4 + 3] = f2bf(w.w * inv);
    }
    ((int4*)a)[tid * 2 + h] = pk.q;
  }
}

__global__ void zero_k(float* p, int n)
{
  int i = blockIdx.x * 256 + threadIdx.x;
  if (i < n) p[i] = 0.f;
}

// scores /= max; softmax; -> FP32 out (2048).
__global__ __launch_bounds__(256) void finalize_k(const float* __restrict__ scores,
                                                  float* __restrict__ out)
{
  const int tid = threadIdx.x;
  float s[8];
  #pragma unroll
  for (int u = 0; u < 8; u++) s[u] = scores[tid + u * 256];

  __shared__ float red[4];

  float m = -3.4e38f;
  #pragma unroll
  for (int u = 0; u < 8; u++) m = fmaxf(m, s[u]);
  #pragma unroll
  for (int off = 32; off > 0; off >>= 1) m = fmaxf(m, __shfl_down(m, off, 64));
  if ((tid & 63) == 0) red[tid >> 6] = m;
  __syncthreads();
  m = fmaxf(fmaxf(red[0], red[1]), fmaxf(red[2], red[3]));
  __syncthreads();

  const float inv1 = 1.f / m;
  #pragma unroll
  for (int u = 0; u < 8; u++) s[u] *= inv1;

  float m2 = -3.4e38f;
  #pragma unroll
  for (int u = 0; u < 8; u++) m2 = fmaxf(m2, s[u]);
  #pragma unroll
  for (int off = 32; off > 0; off >>= 1) m2 = fmaxf(m2, __shfl_down(m2, off, 64));
  if ((tid & 63) == 0) red[tid >> 6] = m2;
  __syncthreads();
  m2 = fmaxf(fmaxf(red[0], red[1]), fmaxf(red[2], red[3]));
  __syncthreads();

  float sum = 0.f;
  #pragma unroll
  for (int u = 0; u < 8; u++) { s[u] = expf(s[u] - m2); sum += s[u]; }
  #pragma unroll
  for (int off = 32; off > 0; off >>= 1) sum += __shfl_down(sum, off, 64);
  if ((tid & 63) == 0) red[tid >> 6] = sum;
  __syncthreads();
  sum = red[0] + red[1] + red[2] + red[3];

  const float invs = 1.f / sum;
  #pragma unroll
  for (int u = 0; u < 8; u++)
    out[tid + u * 256] = s[u] * invs;
}

extern "C" void kernel_launch(void* const* d_in, const int* in_sizes, int n_in,
                              void* d_out, int out_size, void* d_ws, size_t ws_size,
                              hipStream_t stream)
{
  const float* T    = (const float*)d_in[0];   // [2048][4096]
  const float* Win  = (const float*)d_in[1];   // [2048][2048] 'ml'
  const float* Wout = (const float*)d_in[2];   // [2048][4096] 'lc'
  float* out = (float*)d_out;

  const size_t FIX1 = 92274688ull + 16384;
  int R = 1024; bool pre = false;
  if      (ws_size >= FIX1 + (size_t)4096 * 16384) { pre = true; R = 4096; }
  else if (ws_size >= FIX1 + (size_t)2048 * 16384) { pre = true; R = 2048; }
  else if (ws_size >= FIX1 + (size_t)1024 * 16384) { pre = true; R = 1024; }

  unsigned short* Tt = (unsigned short*)d_ws;

  if (pre) {
    unsigned short* Tb    = Tt + (size_t)4096 * 2048;
    unsigned short* Winb  = Tb + (size_t)2048 * 4096;
    unsigned short* Woutb = Winb + (size_t)2048 * 2048;
    unsigned short* comb  = Woutb + (size_t)2048 * 4096;
    float* S      = (float*)(comb + (size_t)4096 * 4096);
    float* scores = S + (size_t)R * 4096;

    zero_k<<<8, 256, 0, stream>>>(scores, 2048);
    transpose_bf16<<<dim3(64, 32), 256, 0, stream>>>(T, Tt);
    cvt_bf16<<<4096, 256, 0, stream>>>(T, Tb, 1048576);
    cvt_bf16<<<2048, 256, 0, stream>>>(Win, Winb, 524288);
    cvt_bf16<<<4096, 256, 0, stream>>>(Wout, Woutb, 1048576);

    // GEMM1: Q -> comb[:,2048:]  (M=4096,N=2048,K=2048 -> 16x16 full fill)
    gemm_n128<1><<<256, 512, 0, stream>>>(
        Tt, Winb, comb + 2048, nullptr, 2048, 2048, 2048, 4096);
    for (int c = 0; c < 4096 / R; c++) {
      const size_t d0 = (size_t)c * R;
      if (R == 4096) {
        // GEMM2 (4096x4096x2048): 256^2 counted-vmcnt template
        gemm256<<<256, 512, 0, stream>>>(
            comb + 2048, Tt, S, 2048, 4096, 2048, 4096);
      } else {
        mfma_gemm<0, 0><<<dim3(32, R / 128), 256, 0, stream>>>(
            comb + d0 * 4096 + 2048, Tt, S, nullptr, 2048, 4096, 2048, 4096);
      }
      softmax_bf16<<<R, 256, 0, stream>>>(S);
      if (R == 4096) {
        // GEMM3 (4096x2048x4096): BM256xBN128 tri-buffered template
        gemm_n128<1><<<256, 512, 0, stream>>>(
            (unsigned short*)S, Tb, comb, nullptr, 4096, 8192, 4096, 4096);
      } else {
        mfma_gemm<0, 1><<<dim3(16, R / 128), 256, 0, stream>>>(
            (unsigned short*)S, Tb, comb + d0 * 4096, nullptr, 4096, 8192, 4096, 4096);
      }
    }
    // GEMM4 (4096x2048x4096, tanh colsum): BM256xBN128 tri-buffered template
    gemm_n128<2><<<256, 512, 0, stream>>>(
        comb, Woutb, nullptr, scores, 4096, 4096, 4096, 4096);
    finalize_k<<<1, 256, 0, stream>>>(scores, out);
  } else {
    // tier0: r12 layout (67,117,056 B proven to fit), inline cvt for fp32 B.
    unsigned short* comb = Tt + (size_t)4096 * 2048;
    float* S      = (float*)(comb + (size_t)4096 * 4096);
    float* scores = S + (size_t)1024 * 4096;

    zero_k<<<8, 256, 0, stream>>>(scores, 2048);
    transpose_bf16<<<dim3(64, 32), 256, 0, stream>>>(T, Tt);

    mfma_gemm<1, 1><<<dim3(16, 32), 256, 0, stream>>>(
        Tt, Win, comb + 2048, nullptr, 2048, 2048, 2048, 4096);
    for (int c = 0; c < 4; c++) {
      const size_t d0 = (size_t)c * 1024;
      mfma_gemm<0, 0><<<dim3(32, 8), 256, 0, stream>>>(
          comb + d0 * 4096 + 2048, Tt, S, nullptr, 2048, 4096, 2048, 4096);
      softmax_bf16<<<1024, 256, 0, stream>>>(S);
      mfma_gemm<1, 1><<<dim3(16, 8), 256, 0, stream>>>(
          (unsigned short*)S, T, comb + d0 * 4096, nullptr, 4096, 8192, 4096, 4096);
    }
    mfma_gemm<1, 2><<<dim3(16, 32), 256, 0, stream>>>(
        comb, Wout, nullptr, scores, 4096, 4096, 4096, 4096);
    finalize_k<<<1, 256, 0, stream>>>(scores, out);
  }
}